// Round 5
// baseline (202.492 us; speedup 1.0000x reference)
//
#include <hip/hip_runtime.h>

#define SEQ 2048
#define EMB 1024
#define HD 64

typedef _Float16 f16x8 __attribute__((ext_vector_type(8)));
typedef _Float16 f16x4 __attribute__((ext_vector_type(4)));
typedef float f32x4 __attribute__((ext_vector_type(4)));

__device__ __forceinline__ f32x4 mfma32(f16x8 a, f16x8 b, f32x4 c) {
    return __builtin_amdgcn_mfma_f32_16x16x32_f16(a, b, c, 0, 0, 0);
}
__device__ __forceinline__ f32x4 mfma16(f16x4 a, f16x4 b, f32x4 c) {
    return __builtin_amdgcn_mfma_f32_16x16x16f16(a, b, c, 0, 0, 0);
}

// ---------------------------------------------------------------------------
// Kernel 0: pack W{q,k,v} f32[1024][64] into MFMA B-fragment order:
// Wf[(m*4+nt)*32 + kc][lane][8] : elem j = W[kc*32 + (lane>>4)*8 + j][nt*16 + (lane&15)]
// ---------------------------------------------------------------------------
__global__ __launch_bounds__(256) void wcvt_kernel(
    const float* __restrict__ Wq, const float* __restrict__ Wk,
    const float* __restrict__ Wv, _Float16* __restrict__ Wf)
{
    const int m = blockIdx.x >> 2, nt = blockIdx.x & 3, kq = blockIdx.y;
    const float* __restrict__ W = (m == 0) ? Wq : (m == 1) ? Wk : Wv;
    const int tid = threadIdx.x;
    #pragma unroll
    for (int i = 0; i < 2; ++i) {
        int linear = i * 256 + tid;
        int kc = kq * 8 + (linear >> 6), ln = linear & 63;
        int q8 = (ln >> 4) * 8, l = ln & 15;
        f16x8 w;
        #pragma unroll
        for (int j = 0; j < 8; ++j)
            w[j] = (_Float16)W[(size_t)(kc * 32 + q8 + j) * 64 + nt * 16 + l];
        *(f16x8*)&Wf[((size_t)((m * 4 + nt) * 32 + kc)) * 512 + (size_t)ln * 8] = w;
    }
}

// ---------------------------------------------------------------------------
// Kernel 1: QKV projection. 512 threads = 8 waves; each wave owns 16 rows x
// full K (no split, no mid-kernel barriers). Depth-2 explicit register
// ping-pong for A (HBM) and B (L2). launch_bounds(512,2) caps VGPR at 256 so
// the allocator cannot collapse the pipeline (R4: collapsed to 80 VGPRs).
// ---------------------------------------------------------------------------
__global__ __launch_bounds__(512, 2) void proj_kernel(
    const float* __restrict__ x, const float* __restrict__ y,
    const _Float16* __restrict__ Wf,
    const float* __restrict__ bq, const float* __restrict__ bk,
    const float* __restrict__ bv,
    _Float16* __restrict__ Qb, _Float16* __restrict__ Kf,
    _Float16* __restrict__ Vf, float* __restrict__ Vts)
{
    const int mode = blockIdx.y;
    const int r0 = blockIdx.x * 128;
    const int tid = threadIdx.x;
    const int wave = tid >> 6, lane = tid & 63;
    const int l15 = lane & 15, quad = lane >> 4;

    __shared__ float TL[128][65];   // epilogue bounce only (33 KB)

    const float* __restrict__ src = mode ? x : y;
    const _Float16* __restrict__ WA = Wf + (mode ? 65536 : 0);
    const _Float16* __restrict__ WB = Wf + 131072;

    f32x4 zero = {0.f, 0.f, 0.f, 0.f};
    f32x4 acc0[4], acc1[4];
    #pragma unroll
    for (int i = 0; i < 4; ++i) { acc0[i] = zero; acc1[i] = zero; }

    const float* arow = src + (size_t)(r0 + wave * 16 + l15) * 1024 + quad * 8;
    const int lo8 = lane * 8;

    float4 Aa0, Aa1, Ab0, Ab1;
    f16x8 BqA[4], BqB[4], BvA[4], BvB[4];

    auto LDA = [&](float4& x0, float4& x1, int ch) {
        const float4* p = (const float4*)(arow + ch * 32);
        x0 = p[0]; x1 = p[1];
    };
    auto LDBq = [&](f16x8* d, int ch) {
        #pragma unroll
        for (int nt = 0; nt < 4; ++nt)
            d[nt] = *(const f16x8*)&WA[((size_t)(nt * 32 + ch)) * 512 + lo8];
    };
    auto LDBv = [&](f16x8* d, int ch) {
        #pragma unroll
        for (int nt = 0; nt < 4; ++nt)
            d[nt] = *(const f16x8*)&WB[((size_t)(nt * 32 + ch)) * 512 + lo8];
    };
    auto CVT = [&](float4 a0, float4 a1) {
        f16x8 af;
        af[0] = (_Float16)a0.x; af[1] = (_Float16)a0.y;
        af[2] = (_Float16)a0.z; af[3] = (_Float16)a0.w;
        af[4] = (_Float16)a1.x; af[5] = (_Float16)a1.y;
        af[6] = (_Float16)a1.z; af[7] = (_Float16)a1.w;
        return af;
    };

    LDA(Aa0, Aa1, 0); LDBq(BqA, 0); if (mode) LDBv(BvA, 0);
    LDA(Ab0, Ab1, 1); LDBq(BqB, 1); if (mode) LDBv(BvB, 1);

    #pragma unroll 1
    for (int ch = 0; ch < 32; ch += 2) {
        // even chunk
        {
            f16x8 af = CVT(Aa0, Aa1);
            #pragma unroll
            for (int nt = 0; nt < 4; ++nt)
                acc0[nt] = mfma32(af, BqA[nt], acc0[nt]);
            if (mode) {
                #pragma unroll
                for (int nt = 0; nt < 4; ++nt)
                    acc1[nt] = mfma32(af, BvA[nt], acc1[nt]);
            }
            const int nx = (ch + 2) & 31;
            LDA(Aa0, Aa1, nx); LDBq(BqA, nx); if (mode) LDBv(BvA, nx);
        }
        // odd chunk
        {
            f16x8 af = CVT(Ab0, Ab1);
            #pragma unroll
            for (int nt = 0; nt < 4; ++nt)
                acc0[nt] = mfma32(af, BqB[nt], acc0[nt]);
            if (mode) {
                #pragma unroll
                for (int nt = 0; nt < 4; ++nt)
                    acc1[nt] = mfma32(af, BvB[nt], acc1[nt]);
            }
            const int nx = (ch + 3) & 31;
            LDA(Ab0, Ab1, nx); LDBq(BqB, nx); if (mode) LDBv(BvB, nx);
        }
    }

    const int bb = r0 >> 11, s0 = r0 & (SEQ - 1);

    if (mode == 0) {
        #pragma unroll
        for (int nt = 0; nt < 4; ++nt) {
            int h = nt * 16 + l15;
            float bs = bq[h];
            #pragma unroll
            for (int r = 0; r < 4; ++r) {
                int row = r0 + wave * 16 + quad * 4 + r;
                Qb[(size_t)row * 64 + h] = (_Float16)(acc0[nt][r] + bs);
            }
        }
    } else {
        // ---- K via TL -> Kf fragment pack ----
        #pragma unroll
        for (int nt = 0; nt < 4; ++nt) {
            float bs = bk[nt * 16 + l15];
            #pragma unroll
            for (int r = 0; r < 4; ++r)
                TL[wave * 16 + quad * 4 + r][nt * 16 + l15] = acc0[nt][r] + bs;
        }
        __syncthreads();
        {
            int c = tid >> 6, ln = tid & 63;
            const int q8 = (ln >> 4) << 3, l = ln & 15;
            #pragma unroll
            for (int half = 0; half < 2; ++half) {
                f16x8 w;
                #pragma unroll
                for (int j = 0; j < 8; ++j)
                    w[j] = (_Float16)TL[c * 16 + l][half * 32 + q8 + j];
                *(f16x8*)&Kf[(((size_t)(bb * 128 + (s0 >> 4) + c)) * 2 + half) * 512 + ln * 8] = w;
            }
        }
        __syncthreads();
        // ---- V via TL -> Vf fragment pack + Vts ----
        #pragma unroll
        for (int nt = 0; nt < 4; ++nt) {
            float bs = bv[nt * 16 + l15];
            #pragma unroll
            for (int r = 0; r < 4; ++r)
                TL[wave * 16 + quad * 4 + r][nt * 16 + l15] = acc1[nt][r] + bs;
        }
        __syncthreads();
        {
            int c2 = tid >> 7, hth = (tid >> 6) & 1, ln = tid & 63;
            #pragma unroll
            for (int p = 0; p < 2; ++p) {
                int ht = hth * 2 + p;
                f16x8 w;
                #pragma unroll
                for (int j = 0; j < 8; ++j)
                    w[j] = (_Float16)TL[c2 * 32 + ((j >> 2) << 4) + ((ln >> 4) << 2) + (j & 3)][ht * 16 + (ln & 15)];
                *(f16x8*)&Vf[(((size_t)(bb * 64 + (s0 >> 5) + c2)) * 4 + ht) * 512 + ln * 8] = w;
            }
            int wv = tid >> 6, h = tid & 63;
            float s = 0.f;
            #pragma unroll
            for (int i = 0; i < 16; ++i) s += TL[wv * 16 + i][h];
            Vts[((size_t)bb * 128 + (s0 >> 4) + wv) * 64 + h] = s;
        }
    }
}

// ---------------------------------------------------------------------------
// Kernel 2: suffix sums of 16-row V tile sums.
// ---------------------------------------------------------------------------
__global__ __launch_bounds__(256) void vsuf_kernel(
    const float* __restrict__ Vts, float* __restrict__ Vsuf)
{
    const int b = blockIdx.x, hh = blockIdx.y;
    const int tid = threadIdx.x;
    const int seg = tid >> 5, hl = tid & 31, h = (hh << 5) + hl;
    __shared__ float segsum[8][33];
    float vals[16];
    const float* src = Vts + ((size_t)b * 128 + seg * 16) * 64 + h;
    float s = 0.f;
    #pragma unroll
    for (int i = 0; i < 16; ++i) { vals[i] = src[i * 64]; s += vals[i]; }
    segsum[seg][hl] = s;
    __syncthreads();
    float run = 0.f;
    #pragma unroll
    for (int ss = 7; ss >= 0; --ss) if (ss > seg) run += segsum[ss][hl];
    float* dst = Vsuf + ((size_t)b * 128 + seg * 16) * 64 + h;
    #pragma unroll
    for (int i = 15; i >= 0; --i) { run += vals[i]; dst[i * 64] = run; }
}

// ---------------------------------------------------------------------------
// Kernel 3: attention. Paired 32-row q-tiles (t, 63-t) -> uniform 65 chunks
// per block; grid (32,B) = 256 blocks. 4 waves split kc2 (stride 4), register
// ping-pong K/V fragments, no k-loop barriers.
// ---------------------------------------------------------------------------
__global__ __launch_bounds__(256, 2) void attn_kernel(
    const _Float16* __restrict__ Qb, const _Float16* __restrict__ Kf,
    const _Float16* __restrict__ Vf, const float* __restrict__ Vsuf,
    float* __restrict__ out)
{
    const int b = blockIdx.y;
    const int tp = blockIdx.x;   // 0..31
    const int tid = threadIdx.x;
    const int wave = tid >> 6, lane = tid & 63;
    const int l15 = lane & 15, quad = lane >> 4;

    __shared__ float part[4][32][68];
    __shared__ float lpart[4][32];

    const f16x4 ONES4 = {(_Float16)1.f, (_Float16)1.f, (_Float16)1.f, (_Float16)1.f};
    f32x4 zero = {0.f, 0.f, 0.f, 0.f};

    const _Float16* __restrict__ kfb = Kf + (size_t)b * 131072 + lane * 8;
    const _Float16* __restrict__ vfb = Vf + (size_t)b * 131072 + lane * 8;

    #pragma unroll 1
    for (int sel = 0; sel < 2; ++sel) {
        const int tq = sel ? (63 - tp) : tp;   // 32-row q-tile index
        const int qbase = tq << 5;
        const int qgA = qbase + l15, qgB = qgA + 16;

        __syncthreads();   // protect part/lpart reuse across sel iterations

        const _Float16* qpA = Qb + ((size_t)(b * SEQ + qbase + l15) << 6);
        const _Float16* qpB = qpA + (16 << 6);
        f16x8 qfA0 = *(const f16x8*)(qpA + quad * 8);
        f16x8 qfA1 = *(const f16x8*)(qpA + 32 + quad * 8);
        f16x8 qfB0 = *(const f16x8*)(qpB + quad * 8);
        f16x8 qfB1 = *(const f16x8*)(qpB + 32 + quad * 8);

        f32x4 accOA[4], accOB[4], accLA = zero, accLB = zero;
        #pragma unroll
        for (int i = 0; i < 4; ++i) { accOA[i] = zero; accOB[i] = zero; }

        f16x8 k0[4], v0[4], k1[4], v1[4];

        auto LDK = [&](f16x8* kd, f16x8* vd, int kc2) {
            const _Float16* kp = kfb + (size_t)kc2 * 2048;
            kd[0] = *(const f16x8*)(kp);
            kd[1] = *(const f16x8*)(kp + 512);
            kd[2] = *(const f16x8*)(kp + 1024);
            kd[3] = *(const f16x8*)(kp + 1536);
            const _Float16* vp = vfb + (size_t)kc2 * 2048;
            vd[0] = *(const f16x8*)(vp);
            vd[1] = *(const f16x8*)(vp + 512);
            vd[2] = *(const f16x8*)(vp + 1024);
            vd[3] = *(const f16x8*)(vp + 1536);
        };

        auto CMP = [&](const f16x8* kd, const f16x8* vd, int kc2) {
            #pragma unroll
            for (int c = 0; c < 2; ++c) {
                f32x4 sA = zero, sB = zero;
                sA = mfma32(kd[2 * c], qfA0, sA);
                sA = mfma32(kd[2 * c + 1], qfA1, sA);
                sB = mfma32(kd[2 * c], qfB0, sB);
                sB = mfma32(kd[2 * c + 1], qfB1, sB);
                const int kqb = (kc2 << 5) + (c << 4) + (quad << 2);
                f16x4 pfA, pfB;
                #pragma unroll
                for (int r = 0; r < 4; ++r) {
                    pfA[r] = (_Float16)((kqb + r <= qgA) ? __expf(sA[r] * 0.125f) : 1.0f);
                    pfB[r] = (_Float16)((kqb + r <= qgB) ? __expf(sB[r] * 0.125f) : 1.0f);
                }
                #pragma unroll
                for (int ht = 0; ht < 4; ++ht) {
                    f16x8 vv = vd[ht];
                    f16x4 vh;
                    if (c == 0) { vh[0] = vv[0]; vh[1] = vv[1]; vh[2] = vv[2]; vh[3] = vv[3]; }
                    else        { vh[0] = vv[4]; vh[1] = vv[5]; vh[2] = vv[6]; vh[3] = vv[7]; }
                    accOA[ht] = mfma16(vh, pfA, accOA[ht]);
                    accOB[ht] = mfma16(vh, pfB, accOB[ht]);
                }
                accLA = mfma16(ONES4, pfA, accLA);
                accLB = mfma16(ONES4, pfB, accLB);
            }
        };

        const int n2 = tq + 1;
        int i = wave;
        LDK(k0, v0, (i < n2) ? i : 0);
        for (; i < n2; i += 8) {
            const int i1 = i + 4;
            LDK(k1, v1, (i1 < n2) ? i1 : i);
            CMP(k0, v0, i);
            const int i2 = i + 8;
            LDK(k0, v0, (i2 < n2) ? i2 : i);
            if (i1 < n2) CMP(k1, v1, i1);
        }

        #pragma unroll
        for (int ht = 0; ht < 4; ++ht)
            #pragma unroll
            for (int r = 0; r < 4; ++r) {
                part[wave][l15][ht * 16 + quad * 4 + r] = accOA[ht][r];
                part[wave][16 + l15][ht * 16 + quad * 4 + r] = accOB[ht][r];
            }
        if (quad == 0) {
            lpart[wave][l15] = accLA[0];
            lpart[wave][16 + l15] = accLB[0];
        }
        __syncthreads();

        {
            const int q = tid >> 3, hb = (tid & 7) << 3;
            f32x4 o0 = zero, o1 = zero;
            float l = 0.f;
            #pragma unroll
            for (int w = 0; w < 4; ++w) {
                l += lpart[w][q];
                o0 = o0 + *(const f32x4*)&part[w][q][hb];
                o1 = o1 + *(const f32x4*)&part[w][q][hb + 4];
            }
            const int tend = 2 * tq + 2;
            const float nOnes = (float)(SEQ - (tend << 4));
            f32x4 cs0 = zero, cs1 = zero;
            if (tend < 128) {
                const float* cp = &Vsuf[((size_t)(b * 128 + tend) << 6) + hb];
                cs0 = *(const f32x4*)(cp);
                cs1 = *(const f32x4*)(cp + 4);
            }
            const float inv = 1.0f / (l + nOnes);
            f32x4 r0 = (o0 + cs0) * inv;
            f32x4 r1 = (o1 + cs1) * inv;
            float* op = &out[((size_t)(b * SEQ + qbase + q) << 6) + hb];
            *(f32x4*)(op) = r0;
            *(f32x4*)(op + 4) = r1;
        }
    }
}

extern "C" void kernel_launch(void* const* d_in, const int* in_sizes, int n_in,
                              void* d_out, int out_size, void* d_ws, size_t ws_size,
                              hipStream_t stream) {
    const float* x  = (const float*)d_in[0];
    const float* y  = (const float*)d_in[1];
    const float* Wq = (const float*)d_in[2];
    const float* bq = (const float*)d_in[3];
    const float* Wk = (const float*)d_in[4];
    const float* bk = (const float*)d_in[5];
    const float* Wv = (const float*)d_in[6];
    const float* bv = (const float*)d_in[7];
    float* out = (float*)d_out;

    char* ws = (char*)d_ws;
    _Float16* Qb  = (_Float16*)(ws);                           // 2 MB
    _Float16* Kf  = (_Float16*)(ws + (1u << 21));              // 2 MB
    _Float16* Vf  = (_Float16*)(ws + (2u << 21));              // 2 MB
    _Float16* Wf  = (_Float16*)(ws + (3u << 21));              // 384 KB
    float*    Vts = (float*)(ws + (3u << 21) + (512u << 10));  // 256 KB
    float*    Vsf = (float*)(ws + (3u << 21) + (768u << 10));  // 256 KB

    wcvt_kernel<<<dim3(12, 4), 256, 0, stream>>>(Wq, Wk, Wv, Wf);
    proj_kernel<<<dim3(128, 2), 512, 0, stream>>>(x, y, Wf, bq, bk, bv, Qb, Kf, Vf, Vts);
    vsuf_kernel<<<dim3(8, 2), 256, 0, stream>>>(Vts, Vsf);
    attn_kernel<<<dim3(32, 8), 256, 0, stream>>>(Qb, Kf, Vf, Vsf, out);
}

// Round 6
// 187.265 us; speedup vs baseline: 1.0813x; 1.0813x over previous
//
#include <hip/hip_runtime.h>

#define SEQ 2048
#define EMB 1024
#define HD 64

typedef _Float16 f16x8 __attribute__((ext_vector_type(8)));
typedef _Float16 f16x4 __attribute__((ext_vector_type(4)));
typedef float f32x4 __attribute__((ext_vector_type(4)));

__device__ __forceinline__ f32x4 mfma32(f16x8 a, f16x8 b, f32x4 c) {
    return __builtin_amdgcn_mfma_f32_16x16x32_f16(a, b, c, 0, 0, 0);
}
__device__ __forceinline__ f32x4 mfma16(f16x4 a, f16x4 b, f32x4 c) {
    return __builtin_amdgcn_mfma_f32_16x16x16f16(a, b, c, 0, 0, 0);
}

__device__ __forceinline__ void gload_lds16(const float* g, float* l) {
    __builtin_amdgcn_global_load_lds(
        (const __attribute__((address_space(1))) unsigned int*)g,
        (__attribute__((address_space(3))) unsigned int*)l, 16, 0, 0);
}

// ---------------------------------------------------------------------------
// Kernel 0: pack W{q,k,v} f32[1024][64] into MFMA B-fragment order:
// Wf[(m*4+nt)*32 + kc][lane][8] : elem j = W[kc*32 + (lane>>4)*8 + j][nt*16 + (lane&15)]
// ---------------------------------------------------------------------------
__global__ __launch_bounds__(256) void wcvt_kernel(
    const float* __restrict__ Wq, const float* __restrict__ Wk,
    const float* __restrict__ Wv, _Float16* __restrict__ Wf)
{
    const int m = blockIdx.x >> 2, nt = blockIdx.x & 3, kq = blockIdx.y;
    const float* __restrict__ W = (m == 0) ? Wq : (m == 1) ? Wk : Wv;
    const int tid = threadIdx.x;
    #pragma unroll
    for (int i = 0; i < 2; ++i) {
        int linear = i * 256 + tid;
        int kc = kq * 8 + (linear >> 6), ln = linear & 63;
        int q8 = (ln >> 4) * 8, l = ln & 15;
        f16x8 w;
        #pragma unroll
        for (int j = 0; j < 8; ++j)
            w[j] = (_Float16)W[(size_t)(kc * 32 + q8 + j) * 64 + nt * 16 + l];
        *(f16x8*)&Wf[((size_t)((m * 4 + nt) * 32 + kc)) * 512 + (size_t)ln * 8] = w;
    }
}

// ---------------------------------------------------------------------------
// Kernel 1: QKV projection via global_load_lds DMA staging (m97 pattern).
// 256 thr = 4 waves x 16 rows, M=64/block, grid (256,2) = 512 blocks.
// Per chunk (BK=64): 16 DMAs -> barrier (drain) -> MFMA from swizzled LDS.
// Cross-block overlap (2 blocks/CU) hides the barrier drain.
// ---------------------------------------------------------------------------
__global__ __launch_bounds__(256, 2) void proj_kernel(
    const float* __restrict__ x, const float* __restrict__ y,
    const _Float16* __restrict__ Wf,
    const float* __restrict__ bq, const float* __restrict__ bk,
    const float* __restrict__ bv,
    _Float16* __restrict__ Qb, _Float16* __restrict__ Kf,
    _Float16* __restrict__ Vf, float* __restrict__ Vts)
{
    const int mode = blockIdx.y;
    const int r0 = blockIdx.x * 64;
    const int tid = threadIdx.x;
    const int wave = tid >> 6, lane = tid & 63;
    const int l15 = lane & 15, quad = lane >> 4;

    __shared__ __align__(16) float As[4352];  // 64 rows x 64 cols (swizzled) + TL alias space

    const float* __restrict__ src = mode ? x : y;
    const _Float16* __restrict__ WA = Wf + (mode ? 65536 : 0);
    const _Float16* __restrict__ WB = Wf + 131072;

    f32x4 zero = {0.f, 0.f, 0.f, 0.f};
    f32x4 acc0[4], acc1[4];
    #pragma unroll
    for (int i = 0; i < 4; ++i) { acc0[i] = zero; acc1[i] = zero; }

    // DMA staging geometry: inst j covers rows wave*16+j*4 .. +3, 64 cols.
    // Lane: row = +lane>>4, 16B-unit u = lane&15. 8-float group g stored at
    // swizzled slot g ^ (row&7)  ->  global col = ((u>>1) ^ (row&7))*8 + (u&1)*4.
    const int jrow = lane >> 4;
    const int gl = (lane & 15) >> 1, gh = lane & 1;
    const int lo8 = lane * 8;

    #pragma unroll 1
    for (int ch = 0; ch < 16; ++ch) {
        // ---- issue DMA stage of chunk ch ----
        #pragma unroll
        for (int j = 0; j < 4; ++j) {
            const int row = wave * 16 + j * 4 + jrow;
            const float* gp = src + (size_t)(r0 + row) * 1024 + ch * 64
                              + ((gl ^ (row & 7)) * 8 + gh * 4);
            gload_lds16(gp, &As[(wave * 16 + j * 4) * 64]);
        }
        // ---- B fragments for this chunk (L2) — issued before the barrier ----
        f16x8 Bq0[4], Bq1[4], Bv0[4], Bv1[4];
        const int kc0 = ch * 2, kc1 = ch * 2 + 1;
        #pragma unroll
        for (int nt = 0; nt < 4; ++nt) {
            Bq0[nt] = *(const f16x8*)&WA[((size_t)(nt * 32 + kc0)) * 512 + lo8];
            Bq1[nt] = *(const f16x8*)&WA[((size_t)(nt * 32 + kc1)) * 512 + lo8];
        }
        if (mode) {
            #pragma unroll
            for (int nt = 0; nt < 4; ++nt) {
                Bv0[nt] = *(const f16x8*)&WB[((size_t)(nt * 32 + kc0)) * 512 + lo8];
                Bv1[nt] = *(const f16x8*)&WB[((size_t)(nt * 32 + kc1)) * 512 + lo8];
            }
        }
        __syncthreads();   // drains DMA (vmcnt0) — data in LDS
        #pragma unroll
        for (int s = 0; s < 2; ++s) {
            const float* ap = &As[(wave * 16 + l15) * 64 + (((s * 4 + quad) ^ (l15 & 7)) * 8)];
            float4 a0 = *(const float4*)ap;
            float4 a1 = *(const float4*)(ap + 4);
            f16x8 af;
            af[0] = (_Float16)a0.x; af[1] = (_Float16)a0.y;
            af[2] = (_Float16)a0.z; af[3] = (_Float16)a0.w;
            af[4] = (_Float16)a1.x; af[5] = (_Float16)a1.y;
            af[6] = (_Float16)a1.z; af[7] = (_Float16)a1.w;
            #pragma unroll
            for (int nt = 0; nt < 4; ++nt)
                acc0[nt] = mfma32(af, s ? Bq1[nt] : Bq0[nt], acc0[nt]);
            if (mode) {
                #pragma unroll
                for (int nt = 0; nt < 4; ++nt)
                    acc1[nt] = mfma32(af, s ? Bv1[nt] : Bv0[nt], acc1[nt]);
            }
        }
        __syncthreads();   // all reads done before next chunk's DMA overwrites
    }

    const int bb = r0 >> 11, s0 = r0 & (SEQ - 1);
    float (*TL)[65] = (float(*)[65])As;

    if (mode == 0) {
        #pragma unroll
        for (int nt = 0; nt < 4; ++nt) {
            int h = nt * 16 + l15;
            float bs = bq[h];
            #pragma unroll
            for (int r = 0; r < 4; ++r) {
                int row = r0 + wave * 16 + quad * 4 + r;
                Qb[(size_t)row * 64 + h] = (_Float16)(acc0[nt][r] + bs);
            }
        }
    } else {
        // ---- K via TL -> Kf fragment pack ----
        #pragma unroll
        for (int nt = 0; nt < 4; ++nt) {
            float bs = bk[nt * 16 + l15];
            #pragma unroll
            for (int r = 0; r < 4; ++r)
                TL[wave * 16 + quad * 4 + r][nt * 16 + l15] = acc0[nt][r] + bs;
        }
        __syncthreads();
        {
            int c = tid >> 6, ln = tid & 63;
            const int q8 = (ln >> 4) << 3, l = ln & 15;
            #pragma unroll
            for (int half = 0; half < 2; ++half) {
                f16x8 w;
                #pragma unroll
                for (int j = 0; j < 8; ++j)
                    w[j] = (_Float16)TL[c * 16 + l][half * 32 + q8 + j];
                *(f16x8*)&Kf[(((size_t)(bb * 128 + (s0 >> 4) + c)) * 2 + half) * 512 + ln * 8] = w;
            }
        }
        __syncthreads();
        // ---- V via TL -> Vf fragment pack + Vts ----
        #pragma unroll
        for (int nt = 0; nt < 4; ++nt) {
            float bs = bv[nt * 16 + l15];
            #pragma unroll
            for (int r = 0; r < 4; ++r)
                TL[wave * 16 + quad * 4 + r][nt * 16 + l15] = acc1[nt][r] + bs;
        }
        __syncthreads();
        {
            int c2 = tid >> 7, hth = (tid >> 6) & 1, ln = tid & 63;
            #pragma unroll
            for (int p = 0; p < 2; ++p) {
                int ht = hth * 2 + p;
                f16x8 w;
                #pragma unroll
                for (int j = 0; j < 8; ++j)
                    w[j] = (_Float16)TL[c2 * 32 + ((j >> 2) << 4) + ((ln >> 4) << 2) + (j & 3)][ht * 16 + (ln & 15)];
                *(f16x8*)&Vf[(((size_t)(bb * 64 + (s0 >> 5) + c2)) * 4 + ht) * 512 + ln * 8] = w;
            }
            int wv = tid >> 6, h = tid & 63;
            float s = 0.f;
            #pragma unroll
            for (int i = 0; i < 16; ++i) s += TL[wv * 16 + i][h];
            Vts[((size_t)bb * 128 + (s0 >> 4) + wv) * 64 + h] = s;
        }
    }
}

// ---------------------------------------------------------------------------
// Kernel 2: suffix sums of 16-row V tile sums.
// ---------------------------------------------------------------------------
__global__ __launch_bounds__(256) void vsuf_kernel(
    const float* __restrict__ Vts, float* __restrict__ Vsuf)
{
    const int b = blockIdx.x, hh = blockIdx.y;
    const int tid = threadIdx.x;
    const int seg = tid >> 5, hl = tid & 31, h = (hh << 5) + hl;
    __shared__ float segsum[8][33];
    float vals[16];
    const float* src = Vts + ((size_t)b * 128 + seg * 16) * 64 + h;
    float s = 0.f;
    #pragma unroll
    for (int i = 0; i < 16; ++i) { vals[i] = src[i * 64]; s += vals[i]; }
    segsum[seg][hl] = s;
    __syncthreads();
    float run = 0.f;
    #pragma unroll
    for (int ss = 7; ss >= 0; --ss) if (ss > seg) run += segsum[ss][hl];
    float* dst = Vsuf + ((size_t)b * 128 + seg * 16) * 64 + h;
    #pragma unroll
    for (int i = 15; i >= 0; --i) { run += vals[i]; dst[i * 64] = run; }
}

// ---------------------------------------------------------------------------
// Kernel 3: attention. One 32-row q-tile per block, grid (64,B) = 512 blocks
// (2 blocks/CU), REVERSED order so heavy blocks launch first and the HW
// scheduler backfills. 4 waves split kc2 chunks stride 4; register ping-pong;
// no k-loop barriers.
// ---------------------------------------------------------------------------
__global__ __launch_bounds__(256, 2) void attn_kernel(
    const _Float16* __restrict__ Qb, const _Float16* __restrict__ Kf,
    const _Float16* __restrict__ Vf, const float* __restrict__ Vsuf,
    float* __restrict__ out)
{
    const int b = blockIdx.y;
    const int tq = 63 - blockIdx.x;   // heavy tiles first
    const int tid = threadIdx.x;
    const int wave = tid >> 6, lane = tid & 63;
    const int l15 = lane & 15, quad = lane >> 4;

    __shared__ float part[4][32][68];
    __shared__ float lpart[4][32];

    const f16x4 ONES4 = {(_Float16)1.f, (_Float16)1.f, (_Float16)1.f, (_Float16)1.f};
    f32x4 zero = {0.f, 0.f, 0.f, 0.f};

    const _Float16* __restrict__ kfb = Kf + (size_t)b * 131072 + lane * 8;
    const _Float16* __restrict__ vfb = Vf + (size_t)b * 131072 + lane * 8;

    const int qbase = tq << 5;
    const int qgA = qbase + l15, qgB = qgA + 16;

    const _Float16* qpA = Qb + ((size_t)(b * SEQ + qbase + l15) << 6);
    const _Float16* qpB = qpA + (16 << 6);
    f16x8 qfA0 = *(const f16x8*)(qpA + quad * 8);
    f16x8 qfA1 = *(const f16x8*)(qpA + 32 + quad * 8);
    f16x8 qfB0 = *(const f16x8*)(qpB + quad * 8);
    f16x8 qfB1 = *(const f16x8*)(qpB + 32 + quad * 8);

    f32x4 accOA[4], accOB[4], accLA = zero, accLB = zero;
    #pragma unroll
    for (int i = 0; i < 4; ++i) { accOA[i] = zero; accOB[i] = zero; }

    f16x8 k0[4], v0[4], k1[4], v1[4];

    auto LDK = [&](f16x8* kd, f16x8* vd, int kc2) {
        const _Float16* kp = kfb + (size_t)kc2 * 2048;
        kd[0] = *(const f16x8*)(kp);
        kd[1] = *(const f16x8*)(kp + 512);
        kd[2] = *(const f16x8*)(kp + 1024);
        kd[3] = *(const f16x8*)(kp + 1536);
        const _Float16* vp = vfb + (size_t)kc2 * 2048;
        vd[0] = *(const f16x8*)(vp);
        vd[1] = *(const f16x8*)(vp + 512);
        vd[2] = *(const f16x8*)(vp + 1024);
        vd[3] = *(const f16x8*)(vp + 1536);
    };

    auto CMP = [&](const f16x8* kd, const f16x8* vd, int kc2) {
        #pragma unroll
        for (int c = 0; c < 2; ++c) {
            f32x4 sA = zero, sB = zero;
            sA = mfma32(kd[2 * c], qfA0, sA);
            sA = mfma32(kd[2 * c + 1], qfA1, sA);
            sB = mfma32(kd[2 * c], qfB0, sB);
            sB = mfma32(kd[2 * c + 1], qfB1, sB);
            const int kqb = (kc2 << 5) + (c << 4) + (quad << 2);
            f16x4 pfA, pfB;
            #pragma unroll
            for (int r = 0; r < 4; ++r) {
                pfA[r] = (_Float16)((kqb + r <= qgA) ? __expf(sA[r] * 0.125f) : 1.0f);
                pfB[r] = (_Float16)((kqb + r <= qgB) ? __expf(sB[r] * 0.125f) : 1.0f);
            }
            #pragma unroll
            for (int ht = 0; ht < 4; ++ht) {
                f16x8 vv = vd[ht];
                f16x4 vh;
                if (c == 0) { vh[0] = vv[0]; vh[1] = vv[1]; vh[2] = vv[2]; vh[3] = vv[3]; }
                else        { vh[0] = vv[4]; vh[1] = vv[5]; vh[2] = vv[6]; vh[3] = vv[7]; }
                accOA[ht] = mfma16(vh, pfA, accOA[ht]);
                accOB[ht] = mfma16(vh, pfB, accOB[ht]);
            }
            accLA = mfma16(ONES4, pfA, accLA);
            accLB = mfma16(ONES4, pfB, accLB);
        }
    };

    const int n2 = tq + 1;
    int i = wave;
    LDK(k0, v0, (i < n2) ? i : 0);
    for (; i < n2; i += 8) {
        const int i1 = i + 4;
        LDK(k1, v1, (i1 < n2) ? i1 : i);
        CMP(k0, v0, i);
        const int i2 = i + 8;
        LDK(k0, v0, (i2 < n2) ? i2 : i);
        if (i1 < n2) CMP(k1, v1, i1);
    }

    #pragma unroll
    for (int ht = 0; ht < 4; ++ht)
        #pragma unroll
        for (int r = 0; r < 4; ++r) {
            part[wave][l15][ht * 16 + quad * 4 + r] = accOA[ht][r];
            part[wave][16 + l15][ht * 16 + quad * 4 + r] = accOB[ht][r];
        }
    if (quad == 0) {
        lpart[wave][l15] = accLA[0];
        lpart[wave][16 + l15] = accLB[0];
    }
    __syncthreads();

    {
        const int q = tid >> 3, hb = (tid & 7) << 3;
        f32x4 o0 = zero, o1 = zero;
        float l = 0.f;
        #pragma unroll
        for (int w = 0; w < 4; ++w) {
            l += lpart[w][q];
            o0 = o0 + *(const f32x4*)&part[w][q][hb];
            o1 = o1 + *(const f32x4*)&part[w][q][hb + 4];
        }
        const int tend = 2 * tq + 2;
        const float nOnes = (float)(SEQ - (tend << 4));
        f32x4 cs0 = zero, cs1 = zero;
        if (tend < 128) {
            const float* cp = &Vsuf[((size_t)(b * 128 + tend) << 6) + hb];
            cs0 = *(const f32x4*)(cp);
            cs1 = *(const f32x4*)(cp + 4);
        }
        const float inv = 1.0f / (l + nOnes);
        f32x4 r0 = (o0 + cs0) * inv;
        f32x4 r1 = (o1 + cs1) * inv;
        float* op = &out[((size_t)(b * SEQ + qbase + q) << 6) + hb];
        *(f32x4*)(op) = r0;
        *(f32x4*)(op + 4) = r1;
    }
}

extern "C" void kernel_launch(void* const* d_in, const int* in_sizes, int n_in,
                              void* d_out, int out_size, void* d_ws, size_t ws_size,
                              hipStream_t stream) {
    const float* x  = (const float*)d_in[0];
    const float* y  = (const float*)d_in[1];
    const float* Wq = (const float*)d_in[2];
    const float* bq = (const float*)d_in[3];
    const float* Wk = (const float*)d_in[4];
    const float* bk = (const float*)d_in[5];
    const float* Wv = (const float*)d_in[6];
    const float* bv = (const float*)d_in[7];
    float* out = (float*)d_out;

    char* ws = (char*)d_ws;
    _Float16* Qb  = (_Float16*)(ws);                           // 2 MB
    _Float16* Kf  = (_Float16*)(ws + (1u << 21));              // 2 MB
    _Float16* Vf  = (_Float16*)(ws + (2u << 21));              // 2 MB
    _Float16* Wf  = (_Float16*)(ws + (3u << 21));              // 384 KB
    float*    Vts = (float*)(ws + (3u << 21) + (512u << 10));  // 256 KB
    float*    Vsf = (float*)(ws + (3u << 21) + (768u << 10));  // 256 KB

    wcvt_kernel<<<dim3(12, 4), 256, 0, stream>>>(Wq, Wk, Wv, Wf);
    proj_kernel<<<dim3(256, 2), 256, 0, stream>>>(x, y, Wf, bq, bk, bv, Qb, Kf, Vf, Vts);
    vsuf_kernel<<<dim3(8, 2), 256, 0, stream>>>(Vts, Vsf);
    attn_kernel<<<dim3(64, 8), 256, 0, stream>>>(Qb, Kf, Vf, Vsf, out);
}